// Round 4
// baseline (172.786 us; speedup 1.0000x reference)
//
#include <hip/hip_runtime.h>

typedef __bf16 v8bf __attribute__((ext_vector_type(8)));
typedef float v4f __attribute__((ext_vector_type(4)));
typedef unsigned short u16x8 __attribute__((ext_vector_type(8)));

__device__ __forceinline__ unsigned short f2bf(float f) {
    unsigned int u = __float_as_uint(f);
    u += 0x7FFFu + ((u >> 16) & 1u);   // round-to-nearest-even
    return (unsigned short)(u >> 16);
}

__device__ __forceinline__ v8bf ld_bf8(const unsigned short* p) {
    u16x8 r = *(const u16x8*)p;
    return __builtin_bit_cast(v8bf, r);
}

// ---------------- Kernel A: build V = U[:, :64] (one column per block) ----------------
__global__ __launch_bounds__(256) void build_V(
        const float* __restrict__ rx0, const float* __restrict__ ry0,
        const float* __restrict__ ry1,
        unsigned short* __restrict__ Vre, unsigned short* __restrict__ Vim)
{
    __shared__ float sre[1024];
    __shared__ float sim[1024];
    const int c = blockIdx.x;     // feature column 0..63
    const int t = threadIdx.x;

    // hoist all params + trig (one latency hit, not 30 serialized ones)
    float cx[10], sx[10], cy0[10], sy0[10], cy1[10], sy1[10];
    #pragma unroll
    for (int j = 0; j < 10; ++j) {
        float hx = 0.5f * rx0[j], h0 = 0.5f * ry0[j], h1 = 0.5f * ry1[j];
        cx[j] = cosf(hx);  sx[j] = sinf(hx);
        cy0[j] = cosf(h0); sy0[j] = sinf(h0);
        cy1[j] = cosf(h1); sy1[j] = sinf(h1);
    }

    #pragma unroll
    for (int k = 0; k < 4; ++k) {
        int i = t + k * 256;
        sre[i] = (i == c) ? 1.0f : 0.0f;
        sim[i] = 0.0f;
    }
    __syncthreads();

    // Stage 1: G_j = RY(ry0_j) * RX(rx0_j) on qubit j (qubit j <-> bit 9-j)
    for (int j = 0; j < 10; ++j) {
        float g00r =  cy0[j] * cx[j], g00i =  sy0[j] * sx[j];
        float g01r = -sy0[j] * cx[j], g01i = -cy0[j] * sx[j];
        float g10r =  sy0[j] * cx[j], g10i = -cy0[j] * sx[j];
        float g11r =  cy0[j] * cx[j], g11i = -sy0[j] * sx[j];
        int p = 9 - j;
        int lowmask = (1 << p) - 1;
        #pragma unroll
        for (int it = 0; it < 2; ++it) {
            int idx = t + it * 256;
            int a = ((idx >> p) << (p + 1)) | (idx & lowmask);
            int b = a | (1 << p);
            float ar = sre[a], ai = sim[a], br = sre[b], bi = sim[b];
            sre[a] = g00r*ar - g00i*ai + g01r*br - g01i*bi;
            sim[a] = g00r*ai + g00i*ar + g01r*bi + g01i*br;
            sre[b] = g10r*ar - g10i*ai + g11r*br - g11i*bi;
            sim[b] = g10r*ai + g10i*ar + g11r*bi + g11i*br;
        }
        __syncthreads();
    }
    // Stage 2: CNOT ring j -> (j+1)%10
    for (int j = 0; j < 10; ++j) {
        int pc = 9 - j;
        int pt = 9 - ((j + 1) % 10);
        int p1 = pc < pt ? pc : pt;
        int p2 = pc < pt ? pt : pc;
        int x1 = ((t >> p1) << (p1 + 1)) | (t & ((1 << p1) - 1));
        int x2 = ((x1 >> p2) << (p2 + 1)) | (x1 & ((1 << p2) - 1));
        int i0 = x2 | (1 << pc);          // control=1, target=0
        int i1 = i0 | (1 << pt);
        float r0 = sre[i0], q0 = sim[i0];
        sre[i0] = sre[i1]; sim[i0] = sim[i1];
        sre[i1] = r0;      sim[i1] = q0;
        __syncthreads();
    }
    // Stage 3: RY(ry1_j)
    for (int j = 0; j < 10; ++j) {
        int p = 9 - j;
        int lowmask = (1 << p) - 1;
        #pragma unroll
        for (int it = 0; it < 2; ++it) {
            int idx = t + it * 256;
            int a = ((idx >> p) << (p + 1)) | (idx & lowmask);
            int b = a | (1 << p);
            float ar = sre[a], ai = sim[a], br = sre[b], bi = sim[b];
            sre[a] = cy1[j]*ar - sy1[j]*br;  sim[a] = cy1[j]*ai - sy1[j]*bi;
            sre[b] = sy1[j]*ar + cy1[j]*br;  sim[b] = sy1[j]*ai + cy1[j]*bi;
        }
        __syncthreads();
    }
    #pragma unroll
    for (int k = 0; k < 4; ++k) {
        int i = t + k * 256;
        Vre[i * 64 + c] = f2bf(sre[i]);
        Vim[i * 64 + c] = f2bf(sim[i]);
    }
}

// ---------------- Kernel B: out = WHT_7( fold_128( |xn @ V^T|^2 ) ) ----------------
// 1 wave per block, 16 tokens per wave. No LDS, no barriers.
// Double-buffered register pipeline: chunk c+1's 16 V-fragment loads issued
// before chunk c's MFMAs (fix for round-3's serialized-load latency, VGPR=44).

#define MFMA16(a, b, c) __builtin_amdgcn_mfma_f32_16x16x32_bf16(a, b, c, 0, 0, 0)

// 16 global loads: V fragments for 64-state chunk c (re/im x 2 k-halves x 4 nb)
#define CHUNK_LOAD(buf, c) do {                                              \
    const size_t _base = (size_t)(c) * 4096;                                 \
    _Pragma("unroll")                                                        \
    for (int _nb = 0; _nb < 4; ++_nb) {                                      \
        buf[_nb*4+0] = ld_bf8(vreb + _base + _nb*1024);                      \
        buf[_nb*4+1] = ld_bf8(vreb + _base + _nb*1024 + 32);                 \
        buf[_nb*4+2] = ld_bf8(vimb + _base + _nb*1024);                      \
        buf[_nb*4+3] = ld_bf8(vimb + _base + _nb*1024 + 32);                 \
    } } while (0)

// 16 MFMA + fp32 probs + fold into qacc[(c)&1][nb][r]  (all indices static)
#define CHUNK_MFMA(buf, c) do {                                              \
    _Pragma("unroll")                                                        \
    for (int _nb = 0; _nb < 4; ++_nb) {                                      \
        v4f _z = (v4f){0.f,0.f,0.f,0.f};                                     \
        v4f _r = MFMA16(a0, buf[_nb*4+0], _z);                               \
        _r     = MFMA16(a1, buf[_nb*4+1], _r);                               \
        v4f _q = MFMA16(a0, buf[_nb*4+2], _z);                               \
        _q     = MFMA16(a1, buf[_nb*4+3], _q);                               \
        _Pragma("unroll")                                                    \
        for (int _rr = 0; _rr < 4; ++_rr) {                                  \
            float _p = _r[_rr]*_r[_rr] + _q[_rr]*_q[_rr];                    \
            qacc[(c)&1][_nb][_rr] += _p;                                     \
        }                                                                    \
    } } while (0)

__global__ __launch_bounds__(64, 2) void qsa_fused(
        const float* __restrict__ x,
        const unsigned short* __restrict__ Vre,
        const unsigned short* __restrict__ Vim,
        float* __restrict__ out)
{
    const int l = threadIdx.x;           // 0..63 (one wave)
    const int l15 = l & 15, lh = l >> 4;
    const int m0 = blockIdx.x * 16;      // this wave's 16 token rows

    // ---- load + normalize 16 tokens straight into A-fragments (no LDS) ----
    const float* xrow = x + (size_t)(m0 + l15) * 64;
    float4 v0 = *(const float4*)(xrow + lh * 8);
    float4 v1 = *(const float4*)(xrow + lh * 8 + 4);
    float4 v2 = *(const float4*)(xrow + 32 + lh * 8);
    float4 v3 = *(const float4*)(xrow + 32 + lh * 8 + 4);
    float ss = v0.x*v0.x + v0.y*v0.y + v0.z*v0.z + v0.w*v0.w
             + v1.x*v1.x + v1.y*v1.y + v1.z*v1.z + v1.w*v1.w
             + v2.x*v2.x + v2.y*v2.y + v2.z*v2.z + v2.w*v2.w
             + v3.x*v3.x + v3.y*v3.y + v3.z*v3.z + v3.w*v3.w;
    ss += __shfl_xor(ss, 16);
    ss += __shfl_xor(ss, 32);
    float rn = rsqrtf(ss);
    u16x8 ua0, ua1;
    ua0[0]=f2bf(v0.x*rn); ua0[1]=f2bf(v0.y*rn); ua0[2]=f2bf(v0.z*rn); ua0[3]=f2bf(v0.w*rn);
    ua0[4]=f2bf(v1.x*rn); ua0[5]=f2bf(v1.y*rn); ua0[6]=f2bf(v1.z*rn); ua0[7]=f2bf(v1.w*rn);
    ua1[0]=f2bf(v2.x*rn); ua1[1]=f2bf(v2.y*rn); ua1[2]=f2bf(v2.z*rn); ua1[3]=f2bf(v2.w*rn);
    ua1[4]=f2bf(v3.x*rn); ua1[5]=f2bf(v3.y*rn); ua1[6]=f2bf(v3.z*rn); ua1[7]=f2bf(v3.w*rn);
    const v8bf a0 = __builtin_bit_cast(v8bf, ua0);
    const v8bf a1 = __builtin_bit_cast(v8bf, ua1);

    // per-lane fragment bases (elements): row l15(+nb*16), feat-half lh*8
    const unsigned short* vreb = Vre + (size_t)l15 * 64 + lh * 8;
    const unsigned short* vimb = Vim + (size_t)l15 * 64 + lh * 8;

    float qacc[2][4][4];     // [j-bit6][nb][token r] — 128-bin fold accumulators
    #pragma unroll
    for (int c1 = 0; c1 < 2; ++c1)
        #pragma unroll
        for (int nb = 0; nb < 4; ++nb)
            #pragma unroll
            for (int rr = 0; rr < 4; ++rr) qacc[c1][nb][rr] = 0.f;

    v8bf bufA[16], bufB[16];

    // ---- software-pipelined main loop: 16 chunks of 64 states ----
    CHUNK_LOAD(bufA, 0);
    #pragma unroll
    for (int it = 0; it < 8; ++it) {
        CHUNK_LOAD(bufB, 2*it + 1);
        CHUNK_MFMA(bufA, 2*it);
        if (it < 7) CHUNK_LOAD(bufA, 2*it + 2);
        CHUNK_MFMA(bufB, 2*it + 1);
    }

    // ---- 7-bit fast WHT per token row: out[t][h] = sum_j q[j] * (-1)^popc(j & (h+1)) ----
    // j = c1*64 + nb*16 + l15; masks h+1 in [1,64] touch only bits 0..6 of the state.
    #pragma unroll
    for (int rr = 0; rr < 4; ++rr) {
        float w[8];
        #pragma unroll
        for (int c1 = 0; c1 < 2; ++c1)
            #pragma unroll
            for (int nb = 0; nb < 4; ++nb) w[c1*4 + nb] = qacc[c1][nb][rr];

        // bit 6 (c1): pairs (i, i+4)
        #pragma unroll
        for (int i = 0; i < 4; ++i) {
            float u = w[i], v = w[i+4];
            w[i] = u + v; w[i+4] = u - v;
        }
        // bit 5 (nb bit1): pairs (0,2),(1,3),(4,6),(5,7)
        #pragma unroll
        for (int g = 0; g < 8; g += 4)
            #pragma unroll
            for (int i = 0; i < 2; ++i) {
                float u = w[g+i], v = w[g+i+2];
                w[g+i] = u + v; w[g+i+2] = u - v;
            }
        // bit 4 (nb bit0): pairs (0,1),(2,3),(4,5),(6,7)
        #pragma unroll
        for (int g = 0; g < 8; g += 2) {
            float u = w[g], v = w[g+1];
            w[g] = u + v; w[g+1] = u - v;
        }
        // bits 3..0 (l15): cross-lane butterflies
        #pragma unroll
        for (int st = 1; st <= 8; st <<= 1) {
            #pragma unroll
            for (int k = 0; k < 8; ++k) {
                float o = __shfl_xor(w[k], st);
                w[k] = (l15 & st) ? (o - w[k]) : (w[k] + o);
            }
        }

        // w[c1*4+nb] = W[m], m = c1*64 + nb*16 + l15;  out[t][h] with h = m-1
        float* orow = out + (size_t)(m0 + lh*4 + rr) * 64;
        #pragma unroll
        for (int nb = 0; nb < 4; ++nb)
            if (nb != 0 || l15 != 0) orow[nb*16 + l15 - 1] = w[nb];   // c1=0, skip m=0
        if (l15 == 0) orow[63] = w[4];                                 // m=64 -> h=63
    }
}

extern "C" void kernel_launch(void* const* d_in, const int* in_sizes, int n_in,
                              void* d_out, int out_size, void* d_ws, size_t ws_size,
                              hipStream_t stream) {
    const float* x   = (const float*)d_in[0];
    const float* rx0 = (const float*)d_in[1];
    const float* ry0 = (const float*)d_in[2];
    const float* ry1 = (const float*)d_in[3];
    float* out = (float*)d_out;

    unsigned short* Vre = (unsigned short*)d_ws;            // 1024*64 bf16
    unsigned short* Vim = Vre + 1024 * 64;                  // 1024*64 bf16

    const int M = in_sizes[0] / 64;                         // tokens (B*T)

    build_V<<<64, 256, 0, stream>>>(rx0, ry0, ry1, Vre, Vim);
    qsa_fused<<<M / 16, 64, 0, stream>>>(x, Vre, Vim, out);
}

// Round 5
// 111.409 us; speedup vs baseline: 1.5509x; 1.5509x over previous
//
#include <hip/hip_runtime.h>

typedef __bf16 v8bf __attribute__((ext_vector_type(8)));
typedef float v4f __attribute__((ext_vector_type(4)));
typedef unsigned short u16x8 __attribute__((ext_vector_type(8)));

__device__ __forceinline__ unsigned short f2bf(float f) {
    unsigned int u = __float_as_uint(f);
    u += 0x7FFFu + ((u >> 16) & 1u);   // round-to-nearest-even
    return (unsigned short)(u >> 16);
}

__device__ __forceinline__ v8bf ld_bf8(const unsigned short* p) {
    u16x8 r = *(const u16x8*)p;
    return __builtin_bit_cast(v8bf, r);
}

// ---------------- Kernel A: build V = U[:, :64], one WAVE per column ----------------
// U = (tensor RY1) * P_cnot * (tensor G),  G_j = RY(ry0_j)*RX(rx0_j).
// P_cnot is a basis permutation; (tensor G)|c> is a product state -> direct formula.
// RY1 layer = 10 independent butterflies: 4 in-register (m bits 6..9) + 6 shfl (bits 0..5).
// No LDS, no barriers.
__global__ __launch_bounds__(64, 2) void build_V(
        const float* __restrict__ rx0, const float* __restrict__ ry0,
        const float* __restrict__ ry1,
        unsigned short* __restrict__ Vre, unsigned short* __restrict__ Vim)
{
    const int c = blockIdx.x;          // column 0..63
    const int lane = threadIdx.x;      // 0..63

    float c1[10], s1[10];
    #pragma unroll
    for (int j = 0; j < 10; ++j) { float h = 0.5f * ry1[j]; c1[j] = cosf(h); s1[j] = sinf(h); }

    // k[q] = Pinv(m), m = lane + 64*q.  Pinv = C0(C1(...C9(m))): apply CNOTs j=9..0,
    // each: bit tb=9-((j+1)%10) ^= bit cb=9-j.
    int kk[16];
    #pragma unroll
    for (int q = 0; q < 16; ++q) {
        int k = lane + (q << 6);
        #pragma unroll
        for (int jj = 9; jj >= 0; --jj) {
            int cb = 9 - jj, tb = 9 - ((jj + 1) % 10);
            k ^= ((k >> cb) & 1) << tb;
        }
        kk[q] = k;
    }

    // acc[q] = prod_j G_j[k_bit(9-j)][c_bit(9-j)]
    float ar[16], ai[16];
    #pragma unroll
    for (int q = 0; q < 16; ++q) { ar[q] = 1.f; ai[q] = 0.f; }

    #pragma unroll
    for (int j = 0; j < 10; ++j) {
        float hx = 0.5f * rx0[j], hy = 0.5f * ry0[j];
        float cx = cosf(hx), sx = sinf(hx), cy = cosf(hy), sy = sinf(hy);
        // G: g00=(cy*cx, sy*sx) g01=(-sy*cx,-cy*sx) g10=(sy*cx,-cy*sx) g11=(cy*cx,-sy*sx)
        int cb = (c >> (9 - j)) & 1;
        float g0r = cb ? (-sy * cx) : (cy * cx);   // row kb=0, col cb
        float g0i = cb ? (-cy * sx) : (sy * sx);
        float g1r = cb ? (cy * cx)  : (sy * cx);   // row kb=1
        float g1i = cb ? (-sy * sx) : (-cy * sx);
        int p = 9 - j;
        #pragma unroll
        for (int q = 0; q < 16; ++q) {
            int kb = (kk[q] >> p) & 1;
            float fr = kb ? g1r : g0r;
            float fi = kb ? g1i : g0i;
            float nr = ar[q] * fr - ai[q] * fi;
            float ni = ar[q] * fi + ai[q] * fr;
            ar[q] = nr; ai[q] = ni;
        }
    }

    // RY1 butterflies on q bits (m bits 6+b, qubit j=3-b): pair (q, q|1<<b), q is bit=0 side.
    #pragma unroll
    for (int b = 0; b < 4; ++b) {
        float cy = c1[3 - b], sy = s1[3 - b];
        #pragma unroll
        for (int q = 0; q < 16; ++q) {
            if (q & (1 << b)) continue;
            int q2 = q | (1 << b);
            float A_r = ar[q], A_i = ai[q], B_r = ar[q2], B_i = ai[q2];
            ar[q]  = cy * A_r - sy * B_r;  ai[q]  = cy * A_i - sy * B_i;
            ar[q2] = sy * A_r + cy * B_r;  ai[q2] = sy * A_i + cy * B_i;
        }
    }
    // RY1 butterflies on lane bits p=5..0 (qubit j=9-p) via shfl_xor.
    #pragma unroll
    for (int p = 5; p >= 0; --p) {
        float cy = c1[9 - p], sy = s1[9 - p];
        int hi = (lane >> p) & 1;
        #pragma unroll
        for (int q = 0; q < 16; ++q) {
            float orr = __shfl_xor(ar[q], 1 << p);
            float oii = __shfl_xor(ai[q], 1 << p);
            ar[q] = hi ? (sy * orr + cy * ar[q]) : (cy * ar[q] - sy * orr);
            ai[q] = hi ? (sy * oii + cy * ai[q]) : (cy * ai[q] - sy * oii);
        }
    }

    #pragma unroll
    for (int q = 0; q < 16; ++q) {
        int i = lane + (q << 6);
        Vre[i * 64 + c] = f2bf(ar[q]);
        Vim[i * 64 + c] = f2bf(ai[q]);
    }
}

// ---------------- Kernel B: out = WHT_7( fold_128( |xn @ VS^T|^2 ) ) ----------------
// VS = [Vre; Vim] stacked 2048x64 (row 1024+i folds into the same bin as row i).
// Block = 4 waves, ONE 16-token tile, split-K: wave w owns stacked chunks 8w..8w+7.
// Fold accumulators qE/qO selected by compile-time chunk parity (no runtime reg idx).
#define MFMA16(a, b, c) __builtin_amdgcn_mfma_f32_16x16x32_bf16(a, b, c, 0, 0, 0)

#define CLOAD(buf, cc) do {                                                  \
    const unsigned short* _p = vsb + (size_t)(cc) * 4096;                    \
    _Pragma("unroll")                                                        \
    for (int _nb = 0; _nb < 4; ++_nb) {                                      \
        buf[_nb*2+0] = ld_bf8(_p + _nb*1024);                                \
        buf[_nb*2+1] = ld_bf8(_p + _nb*1024 + 32);                           \
    } } while (0)

#define CMFMA(buf, qq) do {                                                  \
    _Pragma("unroll")                                                        \
    for (int _nb = 0; _nb < 4; ++_nb) {                                      \
        v4f _z = (v4f){0.f,0.f,0.f,0.f};                                     \
        v4f _r = MFMA16(a0, buf[_nb*2+0], _z);                               \
        _r     = MFMA16(a1, buf[_nb*2+1], _r);                               \
        _Pragma("unroll")                                                    \
        for (int _rr = 0; _rr < 4; ++_rr)                                    \
            qq[_nb][_rr] += _r[_rr]*_r[_rr];                                 \
    } } while (0)

__global__ __launch_bounds__(256, 3) void qsa_fused(
        const float* __restrict__ x,
        const unsigned short* __restrict__ VS,
        float* __restrict__ out)
{
    __shared__ float part[4][8][16][17];   // [wave][c1*4+nb][token][l15], padded

    const int tid = threadIdx.x;
    const int w = tid >> 6;
    const int l = tid & 63;
    const int l15 = l & 15, lh = l >> 4;
    const int m0 = blockIdx.x * 16;

    // ---- load + normalize 16 tokens into A-fragments (all 4 waves identical) ----
    const float* xrow = x + (size_t)(m0 + l15) * 64;
    float4 v0 = *(const float4*)(xrow + lh * 8);
    float4 v1 = *(const float4*)(xrow + lh * 8 + 4);
    float4 v2 = *(const float4*)(xrow + 32 + lh * 8);
    float4 v3 = *(const float4*)(xrow + 32 + lh * 8 + 4);
    float ss = v0.x*v0.x + v0.y*v0.y + v0.z*v0.z + v0.w*v0.w
             + v1.x*v1.x + v1.y*v1.y + v1.z*v1.z + v1.w*v1.w
             + v2.x*v2.x + v2.y*v2.y + v2.z*v2.z + v2.w*v2.w
             + v3.x*v3.x + v3.y*v3.y + v3.z*v3.z + v3.w*v3.w;
    ss += __shfl_xor(ss, 16);
    ss += __shfl_xor(ss, 32);
    float rn = rsqrtf(ss);
    u16x8 ua0, ua1;
    ua0[0]=f2bf(v0.x*rn); ua0[1]=f2bf(v0.y*rn); ua0[2]=f2bf(v0.z*rn); ua0[3]=f2bf(v0.w*rn);
    ua0[4]=f2bf(v1.x*rn); ua0[5]=f2bf(v1.y*rn); ua0[6]=f2bf(v1.z*rn); ua0[7]=f2bf(v1.w*rn);
    ua1[0]=f2bf(v2.x*rn); ua1[1]=f2bf(v2.y*rn); ua1[2]=f2bf(v2.z*rn); ua1[3]=f2bf(v2.w*rn);
    ua1[4]=f2bf(v3.x*rn); ua1[5]=f2bf(v3.y*rn); ua1[6]=f2bf(v3.z*rn); ua1[7]=f2bf(v3.w*rn);
    const v8bf a0 = __builtin_bit_cast(v8bf, ua0);
    const v8bf a1 = __builtin_bit_cast(v8bf, ua1);

    const unsigned short* vsb = VS + (size_t)l15 * 64 + lh * 8;

    float qE[4][4], qO[4][4];
    #pragma unroll
    for (int nb = 0; nb < 4; ++nb)
        #pragma unroll
        for (int rr = 0; rr < 4; ++rr) { qE[nb][rr] = 0.f; qO[nb][rr] = 0.f; }

    v8bf bA[8], bB[8];
    const int cbase = w * 8;           // 8 stacked chunks per wave (even base)

    CLOAD(bA, cbase + 0);
    CLOAD(bB, cbase + 1);
    #pragma unroll
    for (int jj = 0; jj < 8; jj += 2) {
        CMFMA(bA, qE);
        if (jj + 2 < 8) CLOAD(bA, cbase + jj + 2);
        CMFMA(bB, qO);
        if (jj + 3 < 8) CLOAD(bB, cbase + jj + 3);
    }

    // ---- write per-wave partials: bin = c1*64 + nb*16 + l15, token = lh*4+rr ----
    #pragma unroll
    for (int i8 = 0; i8 < 8; ++i8) {
        #pragma unroll
        for (int rr = 0; rr < 4; ++rr)
            part[w][i8][lh*4 + rr][l15] = (i8 < 4) ? qE[i8][rr] : qO[i8 - 4][rr];
    }
    __syncthreads();

    // ---- tail: wave w handles token sub-index rr = w ----
    float t8[8];
    #pragma unroll
    for (int i8 = 0; i8 < 8; ++i8) {
        t8[i8] = part[0][i8][lh*4 + w][l15] + part[1][i8][lh*4 + w][l15]
               + part[2][i8][lh*4 + w][l15] + part[3][i8][lh*4 + w][l15];
    }
    // 7-bit WHT: bins j = c1*64 + nb*16 + l15
    #pragma unroll
    for (int i = 0; i < 4; ++i) {                 // bit6 (c1)
        float u = t8[i], v = t8[i+4];
        t8[i] = u + v; t8[i+4] = u - v;
    }
    #pragma unroll
    for (int g = 0; g < 8; g += 4)                // bit5 (nb bit1)
        #pragma unroll
        for (int i = 0; i < 2; ++i) {
            float u = t8[g+i], v = t8[g+i+2];
            t8[g+i] = u + v; t8[g+i+2] = u - v;
        }
    #pragma unroll
    for (int g = 0; g < 8; g += 2) {              // bit4 (nb bit0)
        float u = t8[g], v = t8[g+1];
        t8[g] = u + v; t8[g+1] = u - v;
    }
    #pragma unroll
    for (int st = 1; st <= 8; st <<= 1) {         // bits 3..0 (l15) cross-lane
        #pragma unroll
        for (int k = 0; k < 8; ++k) {
            float o = __shfl_xor(t8[k], st);
            t8[k] = (l15 & st) ? (o - t8[k]) : (t8[k] + o);
        }
    }
    // t8[c1*4+nb] = W[m], m = c1*64+nb*16+l15; out h = m-1 for m in [1,64]
    float* orow = out + (size_t)(m0 + lh*4 + w) * 64;
    #pragma unroll
    for (int nb = 0; nb < 4; ++nb)
        if (nb != 0 || l15 != 0) orow[nb*16 + l15 - 1] = t8[nb];   // c1=0
    if (l15 == 0) orow[63] = t8[4];                                 // m=64 -> h=63
}

extern "C" void kernel_launch(void* const* d_in, const int* in_sizes, int n_in,
                              void* d_out, int out_size, void* d_ws, size_t ws_size,
                              hipStream_t stream) {
    const float* x   = (const float*)d_in[0];
    const float* rx0 = (const float*)d_in[1];
    const float* ry0 = (const float*)d_in[2];
    const float* ry1 = (const float*)d_in[3];
    float* out = (float*)d_out;

    unsigned short* Vre = (unsigned short*)d_ws;   // 1024x64 bf16
    unsigned short* Vim = Vre + 1024 * 64;         // 1024x64 bf16 (contiguous -> stacked VS)

    const int M = in_sizes[0] / 64;                // tokens (B*T)

    build_V<<<64, 64, 0, stream>>>(rx0, ry0, ry1, Vre, Vim);
    qsa_fused<<<M / 16, 256, 0, stream>>>(x, Vre, out);
}

// Round 6
// 107.726 us; speedup vs baseline: 1.6039x; 1.0342x over previous
//
#include <hip/hip_runtime.h>

typedef __bf16 v8bf __attribute__((ext_vector_type(8)));
typedef float v4f __attribute__((ext_vector_type(4)));
typedef unsigned short u16x8 __attribute__((ext_vector_type(8)));

__device__ __forceinline__ unsigned short f2bf(float f) {
    unsigned int u = __float_as_uint(f);
    u += 0x7FFFu + ((u >> 16) & 1u);   // round-to-nearest-even
    return (unsigned short)(u >> 16);
}

__device__ __forceinline__ v8bf ld_bf8(const unsigned short* p) {
    u16x8 r = *(const u16x8*)p;
    return __builtin_bit_cast(v8bf, r);
}

// ---------------- Kernel A: build V = U[:, :64] ----------------
// 8 blocks x 512 thr. Wave w computes column c = blockIdx*8 + w fully in
// registers (product-state formula + RY1 butterflies), stages packed re|im
// into LDS, then the block writes ROW-segments of 8 contiguous feats (16 B
// per lane per array) -> each 128B output line touched by exactly one block.
__global__ __launch_bounds__(512, 1) void build_V(
        const float* __restrict__ rx0, const float* __restrict__ ry0,
        const float* __restrict__ ry1,
        unsigned short* __restrict__ Vre, unsigned short* __restrict__ Vim)
{
    __shared__ unsigned int colbuf[8][1024];    // re | im<<16
    const int t = threadIdx.x;
    const int w = t >> 6, lane = t & 63;
    const int c0 = blockIdx.x * 8;
    const int c = c0 + w;                       // this wave's column

    float c1[10], s1[10];
    #pragma unroll
    for (int j = 0; j < 10; ++j) { float h = 0.5f * ry1[j]; c1[j] = cosf(h); s1[j] = sinf(h); }

    // k[q] = Pinv(m), m = lane + 64*q (CNOT ring inverse: pure bit-XOR network)
    int kk[16];
    #pragma unroll
    for (int q = 0; q < 16; ++q) {
        int k = lane + (q << 6);
        #pragma unroll
        for (int jj = 9; jj >= 0; --jj) {
            int cb = 9 - jj, tb = 9 - ((jj + 1) % 10);
            k ^= ((k >> cb) & 1) << tb;
        }
        kk[q] = k;
    }

    float ar[16], ai[16];
    #pragma unroll
    for (int q = 0; q < 16; ++q) { ar[q] = 1.f; ai[q] = 0.f; }

    #pragma unroll
    for (int j = 0; j < 10; ++j) {
        float hx = 0.5f * rx0[j], hy = 0.5f * ry0[j];
        float cx = cosf(hx), sx = sinf(hx), cy = cosf(hy), sy = sinf(hy);
        int cb = (c >> (9 - j)) & 1;
        float g0r = cb ? (-sy * cx) : (cy * cx);
        float g0i = cb ? (-cy * sx) : (sy * sx);
        float g1r = cb ? (cy * cx)  : (sy * cx);
        float g1i = cb ? (-sy * sx) : (-cy * sx);
        int p = 9 - j;
        #pragma unroll
        for (int q = 0; q < 16; ++q) {
            int kb = (kk[q] >> p) & 1;
            float fr = kb ? g1r : g0r;
            float fi = kb ? g1i : g0i;
            float nr = ar[q] * fr - ai[q] * fi;
            float ni = ar[q] * fi + ai[q] * fr;
            ar[q] = nr; ai[q] = ni;
        }
    }

    // RY1 butterflies: m bits 6..9 are q bits (qubit j = 3-b)
    #pragma unroll
    for (int b = 0; b < 4; ++b) {
        float cy = c1[3 - b], sy = s1[3 - b];
        #pragma unroll
        for (int q = 0; q < 16; ++q) {
            if (q & (1 << b)) continue;
            int q2 = q | (1 << b);
            float A_r = ar[q], A_i = ai[q], B_r = ar[q2], B_i = ai[q2];
            ar[q]  = cy * A_r - sy * B_r;  ai[q]  = cy * A_i - sy * B_i;
            ar[q2] = sy * A_r + cy * B_r;  ai[q2] = sy * A_i + cy * B_i;
        }
    }
    // m bits 0..5 are lane bits (qubit j = 9-p) via shfl_xor
    #pragma unroll
    for (int p = 5; p >= 0; --p) {
        float cy = c1[9 - p], sy = s1[9 - p];
        int hi = (lane >> p) & 1;
        #pragma unroll
        for (int q = 0; q < 16; ++q) {
            float orr = __shfl_xor(ar[q], 1 << p);
            float oii = __shfl_xor(ai[q], 1 << p);
            ar[q] = hi ? (sy * orr + cy * ar[q]) : (cy * ar[q] - sy * orr);
            ai[q] = hi ? (sy * oii + cy * ai[q]) : (cy * ai[q] - sy * oii);
        }
    }

    #pragma unroll
    for (int q = 0; q < 16; ++q)
        colbuf[w][lane + (q << 6)] = (unsigned)f2bf(ar[q]) | ((unsigned)f2bf(ai[q]) << 16);
    __syncthreads();

    // coalesced write-out: thread handles states i = t, t+512; 8 feats each
    #pragma unroll
    for (int k = 0; k < 2; ++k) {
        int i = t + k * 512;
        u16x8 re, im;
        #pragma unroll
        for (int cl = 0; cl < 8; ++cl) {
            unsigned u = colbuf[cl][i];
            re[cl] = (unsigned short)u;
            im[cl] = (unsigned short)(u >> 16);
        }
        *(u16x8*)(Vre + (size_t)i * 64 + c0) = re;
        *(u16x8*)(Vim + (size_t)i * 64 + c0) = im;
    }
}

// ---------------- Kernel B: out = WHT_7( fold_128( |xn @ VS^T|^2 ) ) ----------------
// VS = [Vre; Vim] stacked 2048x64. Block = 4 waves, one 16-token tile,
// split-K: wave w owns stacked chunks 8w..8w+7. Double-buffered register
// prefetch with sched_barrier(0) pins (anti load-sinking) + setprio on MFMA.
#define MFMA16(a, b, c) __builtin_amdgcn_mfma_f32_16x16x32_bf16(a, b, c, 0, 0, 0)

#define CLOAD(buf, cc) do {                                                  \
    const unsigned short* _p = vsb + (size_t)(cc) * 4096;                    \
    _Pragma("unroll")                                                        \
    for (int _nb = 0; _nb < 4; ++_nb) {                                      \
        buf[_nb*2+0] = ld_bf8(_p + _nb*1024);                                \
        buf[_nb*2+1] = ld_bf8(_p + _nb*1024 + 32);                           \
    }                                                                        \
    __builtin_amdgcn_sched_barrier(0);                                       \
    } while (0)

#define CMFMA(buf, qq) do {                                                  \
    __builtin_amdgcn_s_setprio(1);                                           \
    _Pragma("unroll")                                                        \
    for (int _nb = 0; _nb < 4; ++_nb) {                                      \
        v4f _z = (v4f){0.f,0.f,0.f,0.f};                                     \
        v4f _r = MFMA16(a0, buf[_nb*2+0], _z);                               \
        _r     = MFMA16(a1, buf[_nb*2+1], _r);                               \
        _Pragma("unroll")                                                    \
        for (int _rr = 0; _rr < 4; ++_rr)                                    \
            qq[_nb][_rr] += _r[_rr]*_r[_rr];                                 \
    }                                                                        \
    __builtin_amdgcn_s_setprio(0);                                           \
    } while (0)

__global__ __launch_bounds__(256, 3) void qsa_fused(
        const float* __restrict__ x,
        const unsigned short* __restrict__ VS,
        float* __restrict__ out)
{
    __shared__ float part[4][8][16][17];   // [wave][c1*4+nb][token][l15], padded

    const int tid = threadIdx.x;
    const int w = tid >> 6;
    const int l = tid & 63;
    const int l15 = l & 15, lh = l >> 4;
    const int m0 = blockIdx.x * 16;

    // ---- load + normalize 16 tokens into A-fragments ----
    const float* xrow = x + (size_t)(m0 + l15) * 64;
    float4 v0 = *(const float4*)(xrow + lh * 8);
    float4 v1 = *(const float4*)(xrow + lh * 8 + 4);
    float4 v2 = *(const float4*)(xrow + 32 + lh * 8);
    float4 v3 = *(const float4*)(xrow + 32 + lh * 8 + 4);
    float ss = v0.x*v0.x + v0.y*v0.y + v0.z*v0.z + v0.w*v0.w
             + v1.x*v1.x + v1.y*v1.y + v1.z*v1.z + v1.w*v1.w
             + v2.x*v2.x + v2.y*v2.y + v2.z*v2.z + v2.w*v2.w
             + v3.x*v3.x + v3.y*v3.y + v3.z*v3.z + v3.w*v3.w;
    ss += __shfl_xor(ss, 16);
    ss += __shfl_xor(ss, 32);
    float rn = rsqrtf(ss);
    u16x8 ua0, ua1;
    ua0[0]=f2bf(v0.x*rn); ua0[1]=f2bf(v0.y*rn); ua0[2]=f2bf(v0.z*rn); ua0[3]=f2bf(v0.w*rn);
    ua0[4]=f2bf(v1.x*rn); ua0[5]=f2bf(v1.y*rn); ua0[6]=f2bf(v1.z*rn); ua0[7]=f2bf(v1.w*rn);
    ua1[0]=f2bf(v2.x*rn); ua1[1]=f2bf(v2.y*rn); ua1[2]=f2bf(v2.z*rn); ua1[3]=f2bf(v2.w*rn);
    ua1[4]=f2bf(v3.x*rn); ua1[5]=f2bf(v3.y*rn); ua1[6]=f2bf(v3.z*rn); ua1[7]=f2bf(v3.w*rn);
    const v8bf a0 = __builtin_bit_cast(v8bf, ua0);
    const v8bf a1 = __builtin_bit_cast(v8bf, ua1);

    const unsigned short* vsb = VS + (size_t)l15 * 64 + lh * 8;

    float qE[4][4], qO[4][4];
    #pragma unroll
    for (int nb = 0; nb < 4; ++nb)
        #pragma unroll
        for (int rr = 0; rr < 4; ++rr) { qE[nb][rr] = 0.f; qO[nb][rr] = 0.f; }

    v8bf bA[8], bB[8];
    const int cbase = w * 8;           // 8 stacked chunks per wave (even base)

    CLOAD(bA, cbase + 0);
    CLOAD(bB, cbase + 1);
    #pragma unroll
    for (int jj = 0; jj < 8; jj += 2) {
        CMFMA(bA, qE);
        if (jj + 2 < 8) CLOAD(bA, cbase + jj + 2);
        CMFMA(bB, qO);
        if (jj + 3 < 8) CLOAD(bB, cbase + jj + 3);
    }

    // ---- per-wave partials: bin = c1*64 + nb*16 + l15, token = lh*4+rr ----
    #pragma unroll
    for (int i8 = 0; i8 < 8; ++i8) {
        #pragma unroll
        for (int rr = 0; rr < 4; ++rr)
            part[w][i8][lh*4 + rr][l15] = (i8 < 4) ? qE[i8][rr] : qO[i8 - 4][rr];
    }
    __syncthreads();

    // ---- tail: wave w handles token sub-index rr = w ----
    float t8[8];
    #pragma unroll
    for (int i8 = 0; i8 < 8; ++i8) {
        t8[i8] = part[0][i8][lh*4 + w][l15] + part[1][i8][lh*4 + w][l15]
               + part[2][i8][lh*4 + w][l15] + part[3][i8][lh*4 + w][l15];
    }
    // 7-bit WHT over bins j = c1*64 + nb*16 + l15
    #pragma unroll
    for (int i = 0; i < 4; ++i) {                 // bit6 (c1)
        float u = t8[i], v = t8[i+4];
        t8[i] = u + v; t8[i+4] = u - v;
    }
    #pragma unroll
    for (int g = 0; g < 8; g += 4)                // bit5 (nb bit1)
        #pragma unroll
        for (int i = 0; i < 2; ++i) {
            float u = t8[g+i], v = t8[g+i+2];
            t8[g+i] = u + v; t8[g+i+2] = u - v;
        }
    #pragma unroll
    for (int g = 0; g < 8; g += 2) {              // bit4 (nb bit0)
        float u = t8[g], v = t8[g+1];
        t8[g] = u + v; t8[g+1] = u - v;
    }
    #pragma unroll
    for (int st = 1; st <= 8; st <<= 1) {         // bits 3..0 (l15) cross-lane
        #pragma unroll
        for (int k = 0; k < 8; ++k) {
            float o = __shfl_xor(t8[k], st);
            t8[k] = (l15 & st) ? (o - t8[k]) : (t8[k] + o);
        }
    }
    // t8[c1*4+nb] = W[m], m = c1*64+nb*16+l15; out h = m-1 for m in [1,64]
    float* orow = out + (size_t)(m0 + lh*4 + w) * 64;
    #pragma unroll
    for (int nb = 0; nb < 4; ++nb)
        if (nb != 0 || l15 != 0) orow[nb*16 + l15 - 1] = t8[nb];   // c1=0
    if (l15 == 0) orow[63] = t8[4];                                 // m=64 -> h=63
}

extern "C" void kernel_launch(void* const* d_in, const int* in_sizes, int n_in,
                              void* d_out, int out_size, void* d_ws, size_t ws_size,
                              hipStream_t stream) {
    const float* x   = (const float*)d_in[0];
    const float* rx0 = (const float*)d_in[1];
    const float* ry0 = (const float*)d_in[2];
    const float* ry1 = (const float*)d_in[3];
    float* out = (float*)d_out;

    unsigned short* Vre = (unsigned short*)d_ws;   // 1024x64 bf16
    unsigned short* Vim = Vre + 1024 * 64;         // 1024x64 bf16 (contiguous -> stacked VS)

    const int M = in_sizes[0] / 64;                // tokens (B*T)

    build_V<<<8, 512, 0, stream>>>(rx0, ry0, ry1, Vre, Vim);
    qsa_fused<<<M / 16, 256, 0, stream>>>(x, Vre, out);
}